// Round 1
// baseline (74694.861 us; speedup 1.0000x reference)
//
#include <hip/hip_runtime.h>
#include <math.h>

#define Ssz 2048
#define Bsz 64
#define Isz 256
#define Hsz 512
#define NBLK 256
#define KC0 24   // 768/32 k-chunks, layer0 (256 x + 512 h)
#define KC1 32   // 1024/32 k-chunks, layer1 (512 h0 + 512 h1)

// ws layout (bytes)
#define WB0HI_OFF 0u
#define WB0LO_OFF 786432u
#define WB1HI_OFF 1572864u
#define WB1LO_OFF 2621440u
#define BIAS0_OFF 3670016u
#define BIAS1_OFF 3672064u
#define CNT_OFF   3674112u
#define H0_OFF    3674368u
#define H1_OFF    3936512u

typedef unsigned short u16;
typedef __attribute__((ext_vector_type(8))) short short8;
typedef __attribute__((ext_vector_type(4))) float f4;

__device__ __forceinline__ u16 f2bf(float f) {
  union { float f; unsigned u; } v; v.f = f;
  unsigned r = v.u + 0x7FFFu + ((v.u >> 16) & 1u);
  return (u16)(r >> 16);
}
__device__ __forceinline__ float bf2f(u16 h) {
  union { unsigned u; float f; } v; v.u = ((unsigned)h) << 16;
  return v.f;
}

// Build masked weights in MFMA B-fragment layout (hi/lo bf16 planes) + fused biases.
__global__ void prep_weights(const float* __restrict__ Wih0, const float* __restrict__ Whh0,
                             const float* __restrict__ bih0, const float* __restrict__ bhh0,
                             const float* __restrict__ Wih1, const float* __restrict__ Whh1,
                             const float* __restrict__ bih1, const float* __restrict__ bhh1,
                             const int* __restrict__ mih0, const int* __restrict__ mhh0,
                             const int* __restrict__ mih1, const int* __restrict__ mhh1,
                             char* __restrict__ ws) {
  const int L0E = 768 * 512, L1E = 1024 * 512;
  int e = blockIdx.x * blockDim.x + threadIdx.x;
  if (e >= L0E + L1E + 1024) return;
  if (e < L0E) {
    int f = e >> 9, fe = e & 511;
    int lane = fe >> 3, j = fe & 7;
    int n = lane & 15, q = lane >> 4;
    int nt = f / KC0, kc = f % KC0;
    int u = nt * 16 + n, k = kc * 32 + q * 8 + j;
    float w;
    if (k < 256) w = Wih0[u * 256 + k] * (float)mih0[u * 256 + k];
    else         w = Whh0[u * 512 + (k - 256)] * (float)mhh0[u * 512 + (k - 256)];
    u16 hi = f2bf(w);
    ((u16*)(ws + WB0HI_OFF))[e] = hi;
    ((u16*)(ws + WB0LO_OFF))[e] = f2bf(w - bf2f(hi));
  } else if (e < L0E + L1E) {
    int e1 = e - L0E;
    int f = e1 >> 9, fe = e1 & 511;
    int lane = fe >> 3, j = fe & 7;
    int n = lane & 15, q = lane >> 4;
    int nt = f >> 5, kc = f & 31;
    int u = nt * 16 + n, k = kc * 32 + q * 8 + j;
    float w;
    if (k < 512) w = Wih1[u * 512 + k] * (float)mih1[u * 512 + k];
    else         w = Whh1[u * 512 + (k - 512)] * (float)mhh1[u * 512 + (k - 512)];
    u16 hi = f2bf(w);
    ((u16*)(ws + WB1HI_OFF))[e1] = hi;
    ((u16*)(ws + WB1LO_OFF))[e1] = f2bf(w - bf2f(hi));
  } else {
    int b = e - L0E - L1E;
    if (b < 512) ((float*)(ws + BIAS0_OFF))[b] = bih0[b] + bhh0[b];
    else { int u = b - 512; ((float*)(ws + BIAS1_OFF))[u] = bih1[u] + bhh1[u]; }
  }
}

// Persistent kernel: 256 blocks (one (layer, m-tile, n-tile) each), manual grid barrier per step.
__global__ __launch_bounds__(256, 1) void rnn_persist(const float* __restrict__ x,
                                                      char* __restrict__ ws,
                                                      float* __restrict__ out) {
  const int tid = threadIdx.x;
  const int wg = blockIdx.x;
  const int L = wg >> 7;          // 0..1
  const int mt = (wg >> 5) & 3;   // batch tile (16 b)
  const int nt = wg & 31;         // unit tile (16 u)
  const int b0 = mt * 16;
  const int lane = tid & 63;
  const int wid = tid >> 6;
  const int n = lane & 15;
  const int q = lane >> 4;
  const int KC = L ? KC1 : KC0;

  const u16* __restrict__ WBhi = (const u16*)(ws + (L ? WB1HI_OFF : WB0HI_OFF));
  const u16* __restrict__ WBlo = (const u16*)(ws + (L ? WB1LO_OFF : WB0LO_OFF));
  const float* __restrict__ bias = (const float*)(ws + (L ? BIAS1_OFF : BIAS0_OFF));
  unsigned* cnt = (unsigned*)(ws + CNT_OFF);
  u16 *H0hi[2], *H0lo[2], *H1hi[2], *H1lo[2];
  H0hi[0] = (u16*)(ws + H0_OFF);           H0lo[0] = (u16*)(ws + H0_OFF + 65536);
  H0hi[1] = (u16*)(ws + H0_OFF + 131072);  H0lo[1] = (u16*)(ws + H0_OFF + 196608);
  H1hi[0] = (u16*)(ws + H1_OFF);           H1lo[0] = (u16*)(ws + H1_OFF + 65536);
  H1hi[1] = (u16*)(ws + H1_OFF + 131072);  H1lo[1] = (u16*)(ws + H1_OFF + 196608);

  // 520 = 512 + 8 pad: row stride 1040 B == 260 dw == 4 mod 32 -> max 2-way bank alias (free)
  __shared__ __align__(16) u16 shi[16][520];
  __shared__ __align__(16) u16 slo[16][520];
  __shared__ __align__(16) float red[1024];

  for (int t = 0; t <= Ssz; ++t) {
    const bool active = (L == 0) ? (t < Ssz) : (t >= 1);
    if (active) {
      f4 acc = {0.f, 0.f, 0.f, 0.f};
      for (int c = 0; c < 2; ++c) {
        __syncthreads();  // previous chunk fully consumed
        if (L == 0 && c == 0) {
          // stage x[t] tile (16 b x 256 i), fp32 -> hi/lo bf16
          const int r = tid >> 4, cc = tid & 15;
          const float* sx = x + ((long)t * Bsz + b0 + r) * Isz + cc * 16;
          u16* dh = &shi[r][cc * 16];
          u16* dl = &slo[r][cc * 16];
          #pragma unroll
          for (int j = 0; j < 16; ++j) {
            float f = sx[j];
            u16 hi = f2bf(f);
            dh[j] = hi;
            dl[j] = f2bf(f - bf2f(hi));
          }
        } else {
          // stage 16 b x 512 k from an H state buffer (hi/lo planes)
          const u16 *srch, *srcl;
          if (L == 1 && c == 1) { srch = H1hi[t & 1];       srcl = H1lo[t & 1]; }
          else                  { srch = H0hi[(t - 1) & 1]; srcl = H0lo[(t - 1) & 1]; }
          const int r = tid >> 4, cc = tid & 15;
          const u16* sh = srch + (b0 + r) * Hsz + cc * 32;
          const u16* sl = srcl + (b0 + r) * Hsz + cc * 32;
          u16* dh = &shi[r][cc * 32];
          u16* dl = &slo[r][cc * 32];
          #pragma unroll
          for (int j = 0; j < 4; ++j) {
            *(short8*)(dh + j * 8) = *(const short8*)(sh + j * 8);
            *(short8*)(dl + j * 8) = *(const short8*)(sl + j * 8);
          }
        }
        __syncthreads();
        const int nkc  = (L == 0 && c == 0) ? 8 : 16;
        const int kcg0 = (L == 0) ? (c == 0 ? 0 : 8) : c * 16;
        for (int kcl = wid; kcl < nkc; kcl += 4) {   // K split across 4 waves
          const int kcg = kcg0 + kcl;
          const u16* bh = WBhi + (((nt * KC + kcg) << 6) + lane) * 8;
          const u16* bl = WBlo + (((nt * KC + kcg) << 6) + lane) * 8;
          short8 Bhi = *(const short8*)bh;
          short8 Blo = *(const short8*)bl;
          const int col = kcl * 32 + q * 8;
          short8 Ahi = *(const short8*)&shi[n][col];
          short8 Alo = *(const short8*)&slo[n][col];
          acc = __builtin_amdgcn_mfma_f32_16x16x32_bf16(Ahi, Bhi, acc, 0, 0, 0);
          acc = __builtin_amdgcn_mfma_f32_16x16x32_bf16(Ahi, Blo, acc, 0, 0, 0);
          acc = __builtin_amdgcn_mfma_f32_16x16x32_bf16(Alo, Bhi, acc, 0, 0, 0);
        }
      }
      __syncthreads();
      *(f4*)&red[(wid << 8) + lane * 4] = acc;   // cross-wave K reduction
      __syncthreads();
      float sum = red[tid] + red[256 + tid] + red[512 + tid] + red[768 + tid];
      const int l = tid >> 2, r = tid & 3;
      const int m = ((l >> 4) << 2) + r;       // C/D: row = quad*4 + reg
      const int u = nt * 16 + (l & 15);        //      col = lane & 15
      const int b = b0 + m;
      float val = tanhf(bias[u] + sum);
      u16 hi = f2bf(val);
      u16 lo = f2bf(val - bf2f(hi));
      if (L == 0) {
        H0hi[t & 1][b * Hsz + u] = hi;
        H0lo[t & 1][b * Hsz + u] = lo;
      } else {
        H1hi[(t - 1) & 1][b * Hsz + u] = hi;
        H1lo[(t - 1) & 1][b * Hsz + u] = lo;
        if (t == Ssz) out[b * Hsz + u] = val;
      }
    }
    // device-wide barrier: monotonic counter, thread0 spins, agent-scope fences
    __syncthreads();
    if (tid == 0) {
      __threadfence();
      atomicAdd(cnt, 1u);
      const unsigned target = (unsigned)NBLK * (unsigned)(t + 1);
      while (__hip_atomic_load(cnt, __ATOMIC_ACQUIRE, __HIP_MEMORY_SCOPE_AGENT) < target) {
        __builtin_amdgcn_s_sleep(1);
      }
      __threadfence();
    }
    __syncthreads();
  }
}

extern "C" void kernel_launch(void* const* d_in, const int* in_sizes, int n_in,
                              void* d_out, int out_size, void* d_ws, size_t ws_size,
                              hipStream_t stream) {
  const float* x    = (const float*)d_in[0];
  const float* Wih0 = (const float*)d_in[1];
  const float* Whh0 = (const float*)d_in[2];
  const float* bih0 = (const float*)d_in[3];
  const float* bhh0 = (const float*)d_in[4];
  const float* Wih1 = (const float*)d_in[5];
  const float* Whh1 = (const float*)d_in[6];
  const float* bih1 = (const float*)d_in[7];
  const float* bhh1 = (const float*)d_in[8];
  const int* mih0   = (const int*)d_in[9];
  const int* mhh0   = (const int*)d_in[10];
  const int* mih1   = (const int*)d_in[11];
  const int* mhh1   = (const int*)d_in[12];
  char* ws = (char*)d_ws;

  // zero barrier counter + H state buffers
  hipMemsetAsync(ws + CNT_OFF, 0, 256 + 2 * 262144, stream);

  const int tot = 768 * 512 + 1024 * 512 + 1024;
  prep_weights<<<(tot + 255) / 256, 256, 0, stream>>>(
      Wih0, Whh0, bih0, bhh0, Wih1, Whh1, bih1, bhh1,
      mih0, mhh0, mih1, mhh1, ws);

  rnn_persist<<<NBLK, 256, 0, stream>>>(x, ws, (float*)d_out);
}

// Round 2
// 16619.081 us; speedup vs baseline: 4.4945x; 4.4945x over previous
//
#include <hip/hip_runtime.h>
#include <math.h>

typedef unsigned int u32;
typedef unsigned long long u64;
typedef unsigned short u16;
typedef __attribute__((ext_vector_type(8))) short short8;
typedef __attribute__((ext_vector_type(4))) float f4;
typedef __attribute__((ext_vector_type(4))) u32 u32x4;

#define Ssz 2048
#define Bsz 64
#define Isz 256
#define Hsz 512
#define NBLK 256
#define KC0 24   // 768/32 k-chunks, layer0 (256 x + 512 h)
#define KC1 32   // 1024/32 k-chunks, layer1 (512 h0 + 512 h1)

// ws layout (bytes). Weights stored PACKED: u32 = bf16hi | bf16lo<<16
#define WB0_OFF   0u
#define WB1_OFF   1572864u
#define BIAS0_OFF 3670016u
#define BIAS1_OFF 3672064u
#define CNT_OFF   3674112u
#define H0_OFF    3674368u   // u32 H0[2][64][512] (packed hi|lo), 2*128KB
#define H1_OFF    3936512u   // u32 H1[2][64][512]

#define MFMA(a, b, c) __builtin_amdgcn_mfma_f32_16x16x32_bf16(a, b, c, 0, 0, 0)

__device__ __forceinline__ u16 f2bf(float f) {
  union { float f; u32 u; } v; v.f = f;
  u32 r = v.u + 0x7FFFu + ((v.u >> 16) & 1u);
  return (u16)(r >> 16);
}
__device__ __forceinline__ float bf2f(u16 h) {
  union { u32 u; float f; } v; v.u = ((u32)h) << 16;
  return v.f;
}
__device__ __forceinline__ u32 packbf(float f) {
  u16 hi = f2bf(f);
  u16 lo = f2bf(f - bf2f(hi));
  return (u32)hi | ((u32)lo << 16);
}
// From two packed words (h0|l0<<16),(h1|l1<<16) build hi=(h0,h1) lo=(l0,l1)
__device__ __forceinline__ void unpack2(u32 w0, u32 w1, u32& hi, u32& lo) {
  hi = __builtin_amdgcn_perm(w1, w0, 0x05040100u);
  lo = __builtin_amdgcn_perm(w1, w0, 0x07060302u);
}
__device__ __forceinline__ void cvt2(float a, float b, u32& hi, u32& lo) {
  u16 ha = f2bf(a), hb = f2bf(b);
  u16 la = f2bf(a - bf2f(ha)), lb = f2bf(b - bf2f(hb));
  hi = (u32)ha | ((u32)hb << 16);
  lo = (u32)la | ((u32)lb << 16);
}

union frag { short8 s; u32 w[4]; };

__global__ void prep_weights(const float* __restrict__ Wih0, const float* __restrict__ Whh0,
                             const float* __restrict__ bih0, const float* __restrict__ bhh0,
                             const float* __restrict__ Wih1, const float* __restrict__ Whh1,
                             const float* __restrict__ bih1, const float* __restrict__ bhh1,
                             const int* __restrict__ mih0, const int* __restrict__ mhh0,
                             const int* __restrict__ mih1, const int* __restrict__ mhh1,
                             char* __restrict__ ws) {
  const int L0E = 768 * 512, L1E = 1024 * 512;
  int e = blockIdx.x * blockDim.x + threadIdx.x;
  if (e >= L0E + L1E + 1024) return;
  if (e < L0E) {
    int f = e >> 9, fe = e & 511;
    int lane = fe >> 3, j = fe & 7;
    int n = lane & 15, q = lane >> 4;
    int nt = f / KC0, kc = f % KC0;
    int u = nt * 16 + n, k = kc * 32 + q * 8 + j;
    float w;
    if (k < 256) w = Wih0[u * 256 + k] * (float)mih0[u * 256 + k];
    else         w = Whh0[u * 512 + (k - 256)] * (float)mhh0[u * 512 + (k - 256)];
    ((u32*)(ws + WB0_OFF))[e] = packbf(w);
  } else if (e < L0E + L1E) {
    int e1 = e - L0E;
    int f = e1 >> 9, fe = e1 & 511;
    int lane = fe >> 3, j = fe & 7;
    int n = lane & 15, q = lane >> 4;
    int nt = f >> 5, kc = f & 31;
    int u = nt * 16 + n, k = kc * 32 + q * 8 + j;
    float w;
    if (k < 512) w = Wih1[u * 512 + k] * (float)mih1[u * 512 + k];
    else         w = Whh1[u * 512 + (k - 512)] * (float)mhh1[u * 512 + (k - 512)];
    ((u32*)(ws + WB1_OFF))[e1] = packbf(w);
  } else {
    int b2 = e - L0E - L1E;
    if (b2 < 512) ((float*)(ws + BIAS0_OFF))[b2] = bih0[b2] + bhh0[b2];
    else          ((float*)(ws + BIAS1_OFF))[b2 - 512] = bih1[b2 - 512] + bhh1[b2 - 512];
  }
}

// Grid barrier: monotonic counter at LLC. All data passed between blocks uses
// agent-scope (LLC-bypass) accesses, so NO fences/invalidations are needed:
// __syncthreads' compiler-emitted s_waitcnt vmcnt(0) drains stores to LLC
// before tid0's increment; pollers' later loads issue after the observed flag.
__device__ __forceinline__ void gbar(u32* cnt, int tid, u32 target, bool wait) {
  asm volatile("" ::: "memory");
  __syncthreads();
  if (tid == 0) {
    __hip_atomic_fetch_add(cnt, 1u, __ATOMIC_RELAXED, __HIP_MEMORY_SCOPE_AGENT);
    if (wait) {
      while (__hip_atomic_load(cnt, __ATOMIC_RELAXED, __HIP_MEMORY_SCOPE_AGENT) < target)
        __builtin_amdgcn_s_sleep(1);
    }
  }
  __syncthreads();
  asm volatile("" ::: "memory");
}

template <int L>
__device__ __forceinline__ void epilogue(f4 acc, float* red, float bs, int tid, int b0, int nt,
                                         u32* H0, u32* H1, float* out, int t) {
  const int lane = tid & 63, wid = tid >> 6;
  *(f4*)&red[(wid << 8) + lane * 4] = acc;
  __syncthreads();
  float sum = red[tid] + red[256 + tid] + red[512 + tid] + red[768 + tid];
  const int l = tid >> 2, r = tid & 3;
  const int m = ((l >> 4) << 2) + r;   // C/D: row = quad*4 + reg
  const int u = nt * 16 + (l & 15);    //      col = lane & 15
  const int b = b0 + m;
  float val = tanhf(bs + sum);
  u32 pv = packbf(val);
  if (L == 0) {
    __hip_atomic_store(H0 + (t & 1) * 32768 + b * Hsz + u, pv,
                       __ATOMIC_RELAXED, __HIP_MEMORY_SCOPE_AGENT);
  } else {
    __hip_atomic_store(H1 + ((t - 1) & 1) * 32768 + b * Hsz + u, pv,
                       __ATOMIC_RELAXED, __HIP_MEMORY_SCOPE_AGENT);
    if (t == Ssz) out[b * Hsz + u] = val;
  }
}

__device__ __forceinline__ void run0(const float* __restrict__ x, char* __restrict__ ws,
                                     float* __restrict__ out, int b0, int nt, int tid, float* red) {
  const int lane = tid & 63, wid = tid >> 6;
  const int n = lane & 15, q = lane >> 4;
  const u32* WB = (const u32*)(ws + WB0_OFF);
  u32* cnt = (u32*)(ws + CNT_OFF);
  u32* H0 = (u32*)(ws + H0_OFF);
  u32* H1 = (u32*)(ws + H1_OFF);
  const float bs = ((const float*)(ws + BIAS0_OFF))[nt * 16 + ((tid >> 2) & 15)];

  // weights -> registers, once (cached loads; prep kernel wrote them)
  short8 Whi[6], Wlo[6];
  #pragma unroll
  for (int i = 0; i < 6; ++i) {
    int kcg = wid + 4 * i;
    const u32* p = WB + ((nt * KC0 + kcg) * 64 + lane) * 8;
    u32x4 a = *(const u32x4*)p;
    u32x4 b = *(const u32x4*)(p + 4);
    frag h, l;
    unpack2(a.x, a.y, h.w[0], l.w[0]);
    unpack2(a.z, a.w, h.w[1], l.w[1]);
    unpack2(b.x, b.y, h.w[2], l.w[2]);
    unpack2(b.z, b.w, h.w[3], l.w[3]);
    Whi[i] = h.s; Wlo[i] = l.s;
  }

  f4 xp[2][2];  // x prefetch (one step ahead; read-only, cached loads)
  auto loadx = [&](int t) {
    const float* xb = x + ((long)t * Bsz + b0 + n) * Isz + q * 8;
    #pragma unroll
    for (int i = 0; i < 2; ++i) {
      int kcg = wid + 4 * i;
      xp[i][0] = *(const f4*)(xb + kcg * 32);
      xp[i][1] = *(const f4*)(xb + kcg * 32 + 4);
    }
  };
  loadx(0);

  for (int t = 0; t < Ssz; ++t) {
    // convert prefetched x to hi/lo A-fragments
    short8 Axh[2], Axl[2];
    #pragma unroll
    for (int i = 0; i < 2; ++i) {
      frag h, l;
      #pragma unroll
      for (int v = 0; v < 2; ++v) {
        f4 f = xp[i][v];
        cvt2(f.x, f.y, h.w[2 * v], l.w[2 * v]);
        cvt2(f.z, f.w, h.w[2 * v + 1], l.w[2 * v + 1]);
      }
      Axh[i] = h.s; Axl[i] = l.s;
    }
    // issue ALL h-state loads (LLC-bypass, independent -> full MLP)
    const u32* Hp = H0 + ((t - 1) & 1) * 32768 + (b0 + n) * Hsz + q * 8;
    u64 hb[4][4];
    #pragma unroll
    for (int i = 0; i < 4; ++i) {
      const u64* p = (const u64*)(Hp + (wid + 4 * i) * 32);
      #pragma unroll
      for (int v = 0; v < 4; ++v)
        hb[i][v] = __hip_atomic_load(p + v, __ATOMIC_RELAXED, __HIP_MEMORY_SCOPE_AGENT);
    }
    f4 acc = {0.f, 0.f, 0.f, 0.f};
    #pragma unroll
    for (int i = 0; i < 2; ++i) {
      acc = MFMA(Axh[i], Whi[i], acc);
      acc = MFMA(Axh[i], Wlo[i], acc);
      acc = MFMA(Axl[i], Whi[i], acc);
    }
    #pragma unroll
    for (int i = 0; i < 4; ++i) {
      frag h, l;
      #pragma unroll
      for (int v = 0; v < 4; ++v) {
        u32 w0 = (u32)hb[i][v], w1 = (u32)(hb[i][v] >> 32);
        unpack2(w0, w1, h.w[v], l.w[v]);
      }
      acc = MFMA(h.s, Whi[i + 2], acc);
      acc = MFMA(h.s, Wlo[i + 2], acc);
      acc = MFMA(l.s, Whi[i + 2], acc);
    }
    loadx(t + 1 < Ssz ? t + 1 : 0);
    epilogue<0>(acc, red, bs, tid, b0, nt, H0, H1, out, t);
    gbar(cnt, tid, (u32)NBLK * (u32)(t + 1), t + 1 < Ssz);  // final: arrive-only
  }
}

__device__ __forceinline__ void run1(char* __restrict__ ws, float* __restrict__ out,
                                     int b0, int nt, int tid, float* red) {
  const int lane = tid & 63, wid = tid >> 6;
  const int n = lane & 15, q = lane >> 4;
  const u32* WB = (const u32*)(ws + WB1_OFF);
  u32* cnt = (u32*)(ws + CNT_OFF);
  u32* H0 = (u32*)(ws + H0_OFF);
  u32* H1 = (u32*)(ws + H1_OFF);
  const float bs = ((const float*)(ws + BIAS1_OFF))[nt * 16 + ((tid >> 2) & 15)];

  short8 Whi[8], Wlo[8];
  #pragma unroll
  for (int i = 0; i < 8; ++i) {
    int kcg = wid + 4 * i;
    const u32* p = WB + ((nt * KC1 + kcg) * 64 + lane) * 8;
    u32x4 a = *(const u32x4*)p;
    u32x4 b = *(const u32x4*)(p + 4);
    frag h, l;
    unpack2(a.x, a.y, h.w[0], l.w[0]);
    unpack2(a.z, a.w, h.w[1], l.w[1]);
    unpack2(b.x, b.y, h.w[2], l.w[2]);
    unpack2(b.z, b.w, h.w[3], l.w[3]);
    Whi[i] = h.s; Wlo[i] = l.s;
  }

  gbar(cnt, tid, (u32)NBLK, true);
  for (int t = 1; t <= Ssz; ++t) {
    const u32* base0 = H0 + ((t - 1) & 1) * 32768 + (b0 + n) * Hsz + q * 8;  // y0[t-1]
    const u32* base1 = H1 + (t & 1) * 32768 + (b0 + n) * Hsz + q * 8;        // own h[t-2]
    u64 hb[8][4];
    #pragma unroll
    for (int i = 0; i < 8; ++i) {
      const u32* bp = (i < 4) ? base0 : base1;
      const u64* p = (const u64*)(bp + (wid + 4 * (i & 3)) * 32);
      #pragma unroll
      for (int v = 0; v < 4; ++v)
        hb[i][v] = __hip_atomic_load(p + v, __ATOMIC_RELAXED, __HIP_MEMORY_SCOPE_AGENT);
    }
    f4 acc = {0.f, 0.f, 0.f, 0.f};
    #pragma unroll
    for (int i = 0; i < 8; ++i) {
      frag h, l;
      #pragma unroll
      for (int v = 0; v < 4; ++v) {
        u32 w0 = (u32)hb[i][v], w1 = (u32)(hb[i][v] >> 32);
        unpack2(w0, w1, h.w[v], l.w[v]);
      }
      acc = MFMA(h.s, Whi[i], acc);
      acc = MFMA(h.s, Wlo[i], acc);
      acc = MFMA(l.s, Whi[i], acc);
    }
    epilogue<1>(acc, red, bs, tid, b0, nt, H0, H1, out, t);
    gbar(cnt, tid, (u32)NBLK * (u32)(t + 1), t < Ssz);  // final: arrive-only
  }
}

__global__ __launch_bounds__(256, 1) void rnn_persist(const float* __restrict__ x,
                                                      char* __restrict__ ws,
                                                      float* __restrict__ out) {
  __shared__ float red[1024];
  const int tid = threadIdx.x;
  const int wg = blockIdx.x;
  const int b0 = ((wg >> 5) & 3) * 16;
  const int nt = wg & 31;
  if (wg < 128) run0(x, ws, out, b0, nt, tid, red);
  else          run1(ws, out, b0, nt, tid, red);
}

extern "C" void kernel_launch(void* const* d_in, const int* in_sizes, int n_in,
                              void* d_out, int out_size, void* d_ws, size_t ws_size,
                              hipStream_t stream) {
  const float* x    = (const float*)d_in[0];
  const float* Wih0 = (const float*)d_in[1];
  const float* Whh0 = (const float*)d_in[2];
  const float* bih0 = (const float*)d_in[3];
  const float* bhh0 = (const float*)d_in[4];
  const float* Wih1 = (const float*)d_in[5];
  const float* Whh1 = (const float*)d_in[6];
  const float* bih1 = (const float*)d_in[7];
  const float* bhh1 = (const float*)d_in[8];
  const int* mih0   = (const int*)d_in[9];
  const int* mhh0   = (const int*)d_in[10];
  const int* mih1   = (const int*)d_in[11];
  const int* mhh1   = (const int*)d_in[12];
  char* ws = (char*)d_ws;

  // zero barrier counter + H state buffers (CNT..end of H1 = 256 + 2*256KB)
  hipMemsetAsync(ws + CNT_OFF, 0, 524544, stream);

  const int tot = 768 * 512 + 1024 * 512 + 1024;
  prep_weights<<<(tot + 255) / 256, 256, 0, stream>>>(
      Wih0, Whh0, bih0, bhh0, Wih1, Whh1, bih1, bhh1,
      mih0, mhh0, mih1, mhh1, ws);

  rnn_persist<<<NBLK, 256, 0, stream>>>(x, ws, (float*)d_out);
}

// Round 3
// 16535.901 us; speedup vs baseline: 4.5171x; 1.0050x over previous
//
#include <hip/hip_runtime.h>
#include <math.h>

typedef unsigned int u32;
typedef unsigned long long u64;
typedef unsigned short u16;
typedef __attribute__((ext_vector_type(8))) short short8;
typedef __attribute__((ext_vector_type(4))) float f4;
typedef __attribute__((ext_vector_type(4))) u32 u32x4;

#define Ssz 2048
#define Bsz 64
#define Isz 256
#define Hsz 512
#define KC0 24   // 768/32 k-chunks, layer0 (256 x + 512 h)
#define KC1 32   // 1024/32 k-chunks, layer1 (512 y0 + 512 h1)

// ws layout (bytes). Weights PACKED u32 = bf16hi | bf16lo<<16, B-frag order.
#define WB0_OFF   0u
#define WB1_OFF   1572864u
#define BIAS0_OFF 3670016u
#define BIAS1_OFF 3672064u
#define FLAGS_OFF 3674112u   // per m: 256B region; flags0[8] @+0, flags1[8] @+64
#define H0_OFF    3675136u   // [slot=3][m=4] x 32KB, chunk-major packed u32
#define H1_OFF    4068352u   // [slot=2][m=4] x 32KB
// end: 4330496

#define MFMA(a, b, c) __builtin_amdgcn_mfma_f32_16x16x32_bf16(a, b, c, 0, 0, 0)

__device__ __forceinline__ u16 f2bf(float f) {
  union { float f; u32 u; } v; v.f = f;
  u32 r = v.u + 0x7FFFu + ((v.u >> 16) & 1u);
  return (u16)(r >> 16);
}
__device__ __forceinline__ float bf2f(u16 h) {
  union { u32 u; float f; } v; v.u = ((u32)h) << 16;
  return v.f;
}
__device__ __forceinline__ u32 packbf(float f) {
  u16 hi = f2bf(f);
  u16 lo = f2bf(f - bf2f(hi));
  return (u32)hi | ((u32)lo << 16);
}
__device__ __forceinline__ void unpack2(u32 w0, u32 w1, u32& hi, u32& lo) {
  hi = __builtin_amdgcn_perm(w1, w0, 0x05040100u);
  lo = __builtin_amdgcn_perm(w1, w0, 0x07060302u);
}
__device__ __forceinline__ void cvt2(float a, float b, u32& hi, u32& lo) {
  u16 ha = f2bf(a), hb = f2bf(b);
  u16 la = f2bf(a - bf2f(ha)), lb = f2bf(b - bf2f(hb));
  hi = (u32)ha | ((u32)hb << 16);
  lo = (u32)la | ((u32)lb << 16);
}
__device__ __forceinline__ float ftanh(float xx) {
  float x = fminf(20.f, fmaxf(-20.f, xx));
  float e = __expf(2.f * x);
  return (e - 1.f) / (e + 1.f);
}

union frag { short8 s; u32 w[4]; };

// LLC-coherent (agent-scope, L2-bypass) accessors
__device__ __forceinline__ u64 ald64(const u64* p) {
  return __hip_atomic_load(p, __ATOMIC_RELAXED, __HIP_MEMORY_SCOPE_AGENT);
}
__device__ __forceinline__ u32 ald32(const u32* p) {
  return __hip_atomic_load(p, __ATOMIC_RELAXED, __HIP_MEMORY_SCOPE_AGENT);
}
__device__ __forceinline__ void ast32(u32* p, u32 v) {
  __hip_atomic_store(p, v, __ATOMIC_RELAXED, __HIP_MEMORY_SCOPE_AGENT);
}

__device__ __forceinline__ void poll1(const u32* f, int tgt) {
  if (tgt <= 0) return;
  while (1) {
    int ok = 1;
    #pragma unroll
    for (int i = 0; i < 8; ++i) ok &= ((int)ald32(f + i) >= tgt);
    if (ok) break;
  }
}
__device__ __forceinline__ void poll2(const u32* f0, int t0, const u32* f1, int t1) {
  if (t0 <= 0 && t1 <= 0) return;
  while (1) {
    int ok = 1;
    #pragma unroll
    for (int i = 0; i < 8; ++i) ok &= ((int)ald32(f0 + i) >= t0);
    #pragma unroll
    for (int i = 0; i < 8; ++i) ok &= ((int)ald32(f1 + i) >= t1);
    if (ok) break;
  }
}

__global__ void prep_weights(const float* __restrict__ Wih0, const float* __restrict__ Whh0,
                             const float* __restrict__ bih0, const float* __restrict__ bhh0,
                             const float* __restrict__ Wih1, const float* __restrict__ Whh1,
                             const float* __restrict__ bih1, const float* __restrict__ bhh1,
                             const int* __restrict__ mih0, const int* __restrict__ mhh0,
                             const int* __restrict__ mih1, const int* __restrict__ mhh1,
                             char* __restrict__ ws) {
  const int L0E = 768 * 512, L1E = 1024 * 512;
  int e = blockIdx.x * blockDim.x + threadIdx.x;
  if (e >= L0E + L1E + 1024) return;
  if (e < L0E) {
    int f = e >> 9, fe = e & 511;
    int lane = fe >> 3, j = fe & 7;
    int n = lane & 15, q = lane >> 4;
    int nt = f / KC0, kc = f % KC0;
    int u = nt * 16 + n, k = kc * 32 + q * 8 + j;
    float w;
    if (k < 256) w = Wih0[u * 256 + k] * (float)mih0[u * 256 + k];
    else         w = Whh0[u * 512 + (k - 256)] * (float)mhh0[u * 512 + (k - 256)];
    ((u32*)(ws + WB0_OFF))[e] = packbf(w);
  } else if (e < L0E + L1E) {
    int e1 = e - L0E;
    int f = e1 >> 9, fe = e1 & 511;
    int lane = fe >> 3, j = fe & 7;
    int n = lane & 15, q = lane >> 4;
    int nt = f >> 5, kc = f & 31;
    int u = nt * 16 + n, k = kc * 32 + q * 8 + j;
    float w;
    if (k < 512) w = Wih1[u * 512 + k] * (float)mih1[u * 512 + k];
    else         w = Whh1[u * 512 + (k - 512)] * (float)mhh1[u * 512 + (k - 512)];
    ((u32*)(ws + WB1_OFF))[e1] = packbf(w);
  } else {
    int b2 = e - L0E - L1E;
    if (b2 < 512) ((float*)(ws + BIAS0_OFF))[b2] = bih0[b2] + bhh0[b2];
    else          ((float*)(ws + BIAS1_OFF))[b2 - 512] = bih1[b2 - 512] + bhh1[b2 - 512];
  }
}

// H chunk-major layout per (slot,m) 32KB: elem (b local 0..15, u 0..511) at
// u32 index  c*512 + (b + 16*((u&31)>>3))*8 + (u&7),  c = u>>5.
// A consumer wave's chunk read = 64 lanes x 32B fully contiguous (2KB).

__device__ __forceinline__ void run0(const float* __restrict__ x, char* __restrict__ ws,
                                     int m, int p, int tid, float (*red)[256]) {
  const int w = tid >> 6, lane = tid & 63, n = lane & 15, q = lane >> 4;
  const int nt = p * 4 + (w & 3), ks = w >> 2;
  const int b0 = m * 16;
  const u32* WB = (const u32*)(ws + WB0_OFF);
  u32* flags0 = (u32*)(ws + FLAGS_OFF + m * 256);
  u32* flags1 = flags0 + 16;
  const float bs = ((const float*)(ws + BIAS0_OFF))[nt * 16 + n];

  // weights -> registers (96 VGPR): chunks kcg = 2i+ks
  short8 Whi[12], Wlo[12];
  #pragma unroll
  for (int i = 0; i < 12; ++i) {
    const int kcg = 2 * i + ks;
    const u32* pw = WB + ((nt * KC0 + kcg) * 64 + lane) * 8;
    u32x4 a = *(const u32x4*)pw;
    u32x4 b = *(const u32x4*)(pw + 4);
    frag h, l;
    unpack2(a.x, a.y, h.w[0], l.w[0]);
    unpack2(a.z, a.w, h.w[1], l.w[1]);
    unpack2(b.x, b.y, h.w[2], l.w[2]);
    unpack2(b.z, b.w, h.w[3], l.w[3]);
    Whi[i] = h.s; Wlo[i] = l.s;
  }

  f4 xp[4][2];
  auto loadx = [&](int t) {
    #pragma unroll
    for (int i = 0; i < 4; ++i) {
      const int kcg = 2 * i + ks;
      const float* sx = x + ((long)t * Bsz + b0 + n) * Isz + kcg * 32 + q * 8;
      xp[i][0] = *(const f4*)sx;
      xp[i][1] = *(const f4*)(sx + 4);
    }
  };
  short8 Axh[4], Axl[4];
  auto cvtx = [&]() {
    #pragma unroll
    for (int i = 0; i < 4; ++i) {
      frag h, l;
      #pragma unroll
      for (int v = 0; v < 2; ++v) {
        f4 f = xp[i][v];
        cvt2(f.x, f.y, h.w[2 * v], l.w[2 * v]);
        cvt2(f.z, f.w, h.w[2 * v + 1], l.w[2 * v + 1]);
      }
      Axh[i] = h.s; Axl[i] = l.s;
    }
  };
  loadx(0); cvtx();

  const int cst = (nt * 16 + n) >> 5;           // store chunk (const per wave)
  const int qp = ((nt * 2) + (n >> 3)) & 3;
  const int jj = n & 7;

  for (int t = 0; t < Ssz; ++t) {
    // x-part MFMAs before the gate (independent of h)
    f4 acc = {0.f, 0.f, 0.f, 0.f};
    #pragma unroll
    for (int i = 0; i < 4; ++i) {
      acc = MFMA(Axh[i], Whi[i], acc);
      acc = MFMA(Axh[i], Wlo[i], acc);
      acc = MFMA(Axl[i], Whi[i], acc);
    }
    if (tid == 0) poll2(flags0, t, flags1, t - 2);   // h0[t-1] ready; L1 consumed h0[t-3]
    __syncthreads();
    const u32* rb = (const u32*)(ws + H0_OFF) + (((t + 2) % 3) * 4 + m) * 8192;
    u64 hb[8][4];
    #pragma unroll
    for (int i = 0; i < 8; ++i) {
      const u64* pp = (const u64*)(rb + (2 * i + ks) * 512 + lane * 8);
      #pragma unroll
      for (int v = 0; v < 4; ++v) hb[i][v] = ald64(pp + v);
    }
    loadx(t + 1 < Ssz ? t + 1 : t);   // prefetch next x during compute
    #pragma unroll
    for (int i = 0; i < 8; ++i) {
      frag h, l;
      #pragma unroll
      for (int v = 0; v < 4; ++v)
        unpack2((u32)hb[i][v], (u32)(hb[i][v] >> 32), h.w[v], l.w[v]);
      acc = MFMA(h.s, Whi[4 + i], acc);
      acc = MFMA(h.s, Wlo[4 + i], acc);
      acc = MFMA(l.s, Whi[4 + i], acc);
    }
    // 2-way K reduction + tanh + h0 store
    *(f4*)&red[w][lane * 4] = acc;
    __syncthreads();
    if (w < 4) {
      u32* wb = (u32*)(ws + H0_OFF) + ((t % 3) * 4 + m) * 8192;
      f4 s0 = *(f4*)&red[w][lane * 4];
      f4 s1 = *(f4*)&red[w + 4][lane * 4];
      #pragma unroll
      for (int r = 0; r < 4; ++r) {
        float val = ftanh(bs + s0[r] + s1[r]);
        ast32(wb + cst * 512 + ((q * 4 + r) + 16 * qp) * 8 + jj, packbf(val));
      }
    }
    __syncthreads();                          // vmcnt(0): stores drained to LLC
    if (tid == 0) ast32(flags0 + p, (u32)(t + 1));
    cvtx();                                   // next x (loads already landed)
  }
}

__device__ __forceinline__ void run1(char* __restrict__ ws, float* __restrict__ out,
                                     int m, int p, int tid, float (*red)[256]) {
  const int w = tid >> 6, lane = tid & 63, n = lane & 15, q = lane >> 4;
  const int nt = p * 4 + (w & 3), ks = w >> 2;
  const int b0 = m * 16;
  const u32* WB = (const u32*)(ws + WB1_OFF);
  u32* flags0 = (u32*)(ws + FLAGS_OFF + m * 256);
  u32* flags1 = flags0 + 16;
  const float bs = ((const float*)(ws + BIAS1_OFF))[nt * 16 + n];

  short8 Whi[16], Wlo[16];   // 128 VGPR
  #pragma unroll
  for (int i = 0; i < 16; ++i) {
    const int kcg = 2 * i + ks;
    const u32* pw = WB + ((nt * KC1 + kcg) * 64 + lane) * 8;
    u32x4 a = *(const u32x4*)pw;
    u32x4 b = *(const u32x4*)(pw + 4);
    frag h, l;
    unpack2(a.x, a.y, h.w[0], l.w[0]);
    unpack2(a.z, a.w, h.w[1], l.w[1]);
    unpack2(b.x, b.y, h.w[2], l.w[2]);
    unpack2(b.z, b.w, h.w[3], l.w[3]);
    Whi[i] = h.s; Wlo[i] = l.s;
  }

  const int cst = (nt * 16 + n) >> 5;
  const int qp = ((nt * 2) + (n >> 3)) & 3;
  const int jj = n & 7;

  for (int t = 1; t <= Ssz; ++t) {
    // phase A: own recurrence h1[t-2] — available one own-step early
    if (tid == 0) poll1(flags1, t - 1);
    __syncthreads();
    f4 acc = {0.f, 0.f, 0.f, 0.f};
    {
      const u32* rb = (const u32*)(ws + H1_OFF) + ((t & 1) * 4 + m) * 8192;
      u64 hb[8][4];
      #pragma unroll
      for (int i = 0; i < 8; ++i) {
        const u64* pp = (const u64*)(rb + (2 * i + ks) * 512 + lane * 8);
        #pragma unroll
        for (int v = 0; v < 4; ++v) hb[i][v] = ald64(pp + v);
      }
      #pragma unroll
      for (int i = 0; i < 8; ++i) {
        frag h, l;
        #pragma unroll
        for (int v = 0; v < 4; ++v)
          unpack2((u32)hb[i][v], (u32)(hb[i][v] >> 32), h.w[v], l.w[v]);
        acc = MFMA(h.s, Whi[8 + i], acc);
        acc = MFMA(h.s, Wlo[8 + i], acc);
        acc = MFMA(l.s, Whi[8 + i], acc);
      }
    }
    // phase B: y0[t-1] — the actual gate
    if (tid == 0) poll1(flags0, t);
    __syncthreads();
    {
      const u32* rb = (const u32*)(ws + H0_OFF) + (((t - 1) % 3) * 4 + m) * 8192;
      u64 hb[8][4];
      #pragma unroll
      for (int i = 0; i < 8; ++i) {
        const u64* pp = (const u64*)(rb + (2 * i + ks) * 512 + lane * 8);
        #pragma unroll
        for (int v = 0; v < 4; ++v) hb[i][v] = ald64(pp + v);
      }
      #pragma unroll
      for (int i = 0; i < 8; ++i) {
        frag h, l;
        #pragma unroll
        for (int v = 0; v < 4; ++v)
          unpack2((u32)hb[i][v], (u32)(hb[i][v] >> 32), h.w[v], l.w[v]);
        acc = MFMA(h.s, Whi[i], acc);
        acc = MFMA(h.s, Wlo[i], acc);
        acc = MFMA(l.s, Whi[i], acc);
      }
    }
    *(f4*)&red[w][lane * 4] = acc;
    __syncthreads();
    if (w < 4) {
      u32* wb = (u32*)(ws + H1_OFF) + (((t - 1) & 1) * 4 + m) * 8192;
      f4 s0 = *(f4*)&red[w][lane * 4];
      f4 s1 = *(f4*)&red[w + 4][lane * 4];
      #pragma unroll
      for (int r = 0; r < 4; ++r) {
        float val = ftanh(bs + s0[r] + s1[r]);
        ast32(wb + cst * 512 + ((q * 4 + r) + 16 * qp) * 8 + jj, packbf(val));
        if (t == Ssz) out[(b0 + q * 4 + r) * Hsz + nt * 16 + n] = val;
      }
    }
    __syncthreads();
    if (tid == 0) ast32(flags1 + p, (u32)t);
  }
}

__global__ __launch_bounds__(512, 2) void rnn_persist(const float* __restrict__ x,
                                                      char* __restrict__ ws,
                                                      float* __restrict__ out) {
  __shared__ float red[8][256];
  const int tid = threadIdx.x;
  const int wg = blockIdx.x;
  const int m = (wg >> 3) & 3, p = wg & 7;
  if (wg < 32) run0(x, ws, m, p, tid, red);
  else         run1(ws, out, m, p, tid, red);
}

extern "C" void kernel_launch(void* const* d_in, const int* in_sizes, int n_in,
                              void* d_out, int out_size, void* d_ws, size_t ws_size,
                              hipStream_t stream) {
  const float* x    = (const float*)d_in[0];
  const float* Wih0 = (const float*)d_in[1];
  const float* Whh0 = (const float*)d_in[2];
  const float* bih0 = (const float*)d_in[3];
  const float* bhh0 = (const float*)d_in[4];
  const float* Wih1 = (const float*)d_in[5];
  const float* Whh1 = (const float*)d_in[6];
  const float* bih1 = (const float*)d_in[7];
  const float* bhh1 = (const float*)d_in[8];
  const int* mih0   = (const int*)d_in[9];
  const int* mhh0   = (const int*)d_in[10];
  const int* mih1   = (const int*)d_in[11];
  const int* mhh1   = (const int*)d_in[12];
  char* ws = (char*)d_ws;

  // zero flags + H0(3 slots) + H1(2 slots)
  hipMemsetAsync(ws + FLAGS_OFF, 0, 1024 + 393216 + 262144, stream);

  const int tot = 768 * 512 + 1024 * 512 + 1024;
  prep_weights<<<(tot + 255) / 256, 256, 0, stream>>>(
      Wih0, Whh0, bih0, bhh0, Wih1, Whh1, bih1, bhh1,
      mih0, mhh0, mih1, mhh1, ws);

  rnn_persist<<<64, 512, 0, stream>>>(x, ws, (float*)d_out);
}